// Round 3
// baseline (405.276 us; speedup 1.0000x reference)
//
#include <hip/hip_runtime.h>
#include <stdint.h>

// RelationalNetwork B=8 C=64 O=256 TE=128 GT=FP=256 A=32
// R3: 2 dispatches. k_pre: U/V bf16 (code-dot folded, recomputed per block) +
// W2/W3 transpose + counter zero. k_main: 64-row tiles, 32KiB LDS, swizzle
// f(r)=((r>>2)&3)|((r&1)<<2) (all 3 LDS phases verified <=2 lanes/bank),
// coalesced part buffer (NO atomic adds), last-block-per-batch folds f_phi.

#define NPAIR 32896
#define NTILE 514

using short8  = __attribute__((ext_vector_type(8))) short;
using float4v = __attribute__((ext_vector_type(4))) float;

__device__ __forceinline__ float    asf(unsigned u){ union{unsigned u; float f;}c; c.u=u; return c.f; }
__device__ __forceinline__ unsigned asu(float f){ union{float f; unsigned u;}c; c.f=f; return c.u; }
__device__ __forceinline__ unsigned short f2bf(float f){
    unsigned u = asu(f); u += 0x7FFFu + ((u>>16)&1u); return (unsigned short)(u>>16);
}
// pack two non-negative floats -> bf16x2 (round-half-up via +0x8000), lo in low half
__device__ __forceinline__ unsigned pkhu(float lo, float hi){
    return __builtin_amdgcn_perm(asu(hi)+0x8000u, asu(lo)+0x8000u, 0x07060302u);
}
// relu(u+v) on packed bf16x2 -> packed bf16x2
__device__ __forceinline__ unsigned bfar2(unsigned u, unsigned v){
    float sh = fmaxf(asf(u & 0xffff0000u) + asf(v & 0xffff0000u), 0.f);
    float sl = fmaxf(asf(u << 16)         + asf(v << 16),         0.f);
    return pkhu(sl, sh);
}

// ---- prep: blocks 0..2047 U/V (qb recomputed per block); 2048..2079 W^T ----
__global__ __launch_bounds__(256) void k_pre(
    const float* __restrict__ x, const float* __restrict__ code,
    const float* __restrict__ w1, const float* __restrict__ b1,
    const float* __restrict__ w2, const float* __restrict__ w3,
    unsigned short* __restrict__ ub, unsigned short* __restrict__ vb,
    unsigned short* __restrict__ w2t, unsigned short* __restrict__ w3t,
    int* __restrict__ cnt)
{
    const int bx = blockIdx.x, tid = threadIdx.x;
    if (bx < 2048) {
        const int i = bx & 255, b = bx >> 8, d = tid;
        float su = b1[d];
        const float* cp = code + b * 128;
        #pragma unroll 8
        for (int t = 0; t < 128; ++t) su += cp[t] * w1[(132 + t) * 256 + d];
        float sv = 0.f;
        const float* xp = x + (b * 64) * 256 + i;
        #pragma unroll 4
        for (int c = 0; c < 64; ++c) {
            float xv = xp[c * 256];
            su += xv * w1[c * 256 + d];
            sv += xv * w1[(66 + c) * 256 + d];
        }
        float yy = (float)(i >> 4) * (2.f / 15.f) - 1.f;
        float xx = (float)(i & 15) * (2.f / 15.f) - 1.f;
        su += yy * w1[64 * 256 + d] + xx * w1[65 * 256 + d];
        sv += yy * w1[130 * 256 + d] + xx * w1[131 * 256 + d];
        ub[(b * 256 + i) * 256 + d] = f2bf(su);
        vb[(b * 256 + i) * 256 + d] = f2bf(sv);
    } else {
        if (bx == 2048 && tid < 8) cnt[tid] = 0;
        __shared__ float t[64][65];
        const int id = bx - 2048;
        const float* src = (id >= 16) ? w3 : w2;
        unsigned short* dst = (id >= 16) ? w3t : w2t;
        const int rem = id & 15;
        const int k0 = (rem >> 2) * 64, n0 = (rem & 3) * 64;
        const int tx = tid & 63, ty = tid >> 6;
        #pragma unroll
        for (int r = ty; r < 64; r += 4)
            t[r][tx] = src[(k0 + r) * 256 + n0 + tx];
        __syncthreads();
        #pragma unroll
        for (int r = ty; r < 64; r += 4)
            dst[(n0 + r) * 256 + k0 + tx] = f2bf(t[tx][r]);
    }
}

// ---- fused g_theta L2+L3 + tril row-sum + folded f_phi -------------------
__global__ __launch_bounds__(256, 4) void k_main(
    const unsigned short* __restrict__ ub, const unsigned short* __restrict__ vb,
    const unsigned short* __restrict__ w2t, const unsigned short* __restrict__ w3t,
    const float* __restrict__ b2, const float* __restrict__ b3,
    float* __restrict__ part, int* __restrict__ cnt,
    const float* __restrict__ fw1, const float* __restrict__ fb1,
    const float* __restrict__ fw2, const float* __restrict__ fb2,
    const float* __restrict__ fw3, const float* __restrict__ fb3,
    float* __restrict__ out)
{
    __shared__ unsigned short tile[64 * 256];   // 32 KiB
    __shared__ int lastFlag;
    const int tid  = threadIdx.x;
    const int b    = blockIdx.y, tIdx = blockIdx.x;
    const int lane = tid & 63, wave = tid >> 6;
    const int n0   = wave * 64;
    const int lm   = lane & 15, quad = lane >> 4;

    // ---- build h1 = relu(U_i + V_j) into LDS (bf16 packed math) ----
    {
        const int r = tid >> 2, q4 = tid & 3;
        const int p = tIdx * 64 + r;
        float sq = sqrtf(8.f * (float)p + 1.f);
        int i = (int)((sq - 1.f) * 0.5f);
        while ((i + 1) * (i + 2) / 2 <= p) ++i;
        while (i * (i + 1) / 2 > p) --i;
        const int j = p - i * (i + 1) / 2;
        const unsigned short* up = ub + (b * 256 + i) * 256;
        const unsigned short* vp = vb + (b * 256 + j) * 256;
        const unsigned fk = ((r >> 2) & 3) | ((r & 1) << 2);
        #pragma unroll
        for (int it = 0; it < 8; ++it) {
            const int c = it * 4 + q4;
            uint4 u = *(const uint4*)(up + c * 8);
            uint4 v = *(const uint4*)(vp + c * 8);
            uint4 w;
            w.x = bfar2(u.x, v.x); w.y = bfar2(u.y, v.y);
            w.z = bfar2(u.z, v.z); w.w = bfar2(u.w, v.w);
            *(uint4*)(&tile[r * 256 + ((c ^ fk) << 3)]) = w;
        }
    }
    __syncthreads();

    float b2c[4], b3c[4];
    #pragma unroll
    for (int nt = 0; nt < 4; ++nt) {
        b2c[nt] = b2[n0 + nt * 16 + lm];
        b3c[nt] = b3[n0 + nt * 16 + lm];
    }

    const unsigned fr_a = ((lm >> 2) & 3) | ((lm & 1) << 2);  // A-frag swizzle key
    const float4v zero4 = {0.f, 0.f, 0.f, 0.f};
    float4v acc[4][4];
    #pragma unroll
    for (int mt = 0; mt < 4; ++mt)
        #pragma unroll
        for (int nt = 0; nt < 4; ++nt) acc[mt][nt] = zero4;

    // ---- GEMM1: h2 = h1 @ W2 ----
    const unsigned short* bb2 = w2t + (n0 + lm) * 256 + quad * 8;
    for (int ks = 0; ks < 8; ++ks) {
        short8 bfr[4];
        #pragma unroll
        for (int nt = 0; nt < 4; ++nt)
            bfr[nt] = *(const short8*)(bb2 + nt * 4096 + ks * 32);
        const int coff = (((ks * 4 + quad) ^ fr_a) << 3);
        short8 afr[4];
        #pragma unroll
        for (int mt = 0; mt < 4; ++mt)
            afr[mt] = *(const short8*)(&tile[(mt * 16 + lm) * 256 + coff]);
        #pragma unroll
        for (int mt = 0; mt < 4; ++mt)
            #pragma unroll
            for (int nt = 0; nt < 4; ++nt)
                acc[mt][nt] = __builtin_amdgcn_mfma_f32_16x16x32_bf16(
                    afr[mt], bfr[nt], acc[mt][nt], 0, 0, 0);
    }
    __syncthreads();

    // ---- h2 = relu(acc + b2) -> LDS (paired b32, 2 lanes/bank) ----
    #pragma unroll
    for (int mt = 0; mt < 4; ++mt) {
        #pragma unroll
        for (int nt = 0; nt < 4; ++nt) {
            const int colE = n0 + nt * 16 + (lm & ~1);
            const int cc   = colE >> 3;
            #pragma unroll
            for (int rg = 0; rg < 4; ++rg) {
                const int row = mt * 16 + quad * 4 + rg;
                float v  = fmaxf(acc[mt][nt][rg] + b2c[nt], 0.f);
                float v1 = __shfl_down(v, 1);
                if (!(lm & 1)) {
                    const unsigned wk = (unsigned)quad | ((unsigned)(rg & 1) << 2);
                    *(unsigned*)(&tile[row * 256 + ((cc ^ wk) << 3) + (colE & 7)]) =
                        pkhu(v, v1);
                }
            }
        }
    }
    __syncthreads();

    // ---- GEMM2: rel = h2 @ W3 ----
    #pragma unroll
    for (int mt = 0; mt < 4; ++mt)
        #pragma unroll
        for (int nt = 0; nt < 4; ++nt) acc[mt][nt] = zero4;

    const unsigned short* bb3 = w3t + (n0 + lm) * 256 + quad * 8;
    for (int ks = 0; ks < 8; ++ks) {
        short8 bfr[4];
        #pragma unroll
        for (int nt = 0; nt < 4; ++nt)
            bfr[nt] = *(const short8*)(bb3 + nt * 4096 + ks * 32);
        const int coff = (((ks * 4 + quad) ^ fr_a) << 3);
        short8 afr[4];
        #pragma unroll
        for (int mt = 0; mt < 4; ++mt)
            afr[mt] = *(const short8*)(&tile[(mt * 16 + lm) * 256 + coff]);
        #pragma unroll
        for (int mt = 0; mt < 4; ++mt)
            #pragma unroll
            for (int nt = 0; nt < 4; ++nt)
                acc[mt][nt] = __builtin_amdgcn_mfma_f32_16x16x32_bf16(
                    afr[mt], bfr[nt], acc[mt][nt], 0, 0, 0);
    }

    // ---- relu + row-sum -> coalesced partials ----
    #pragma unroll
    for (int nt = 0; nt < 4; ++nt) {
        float s = 0.f;
        #pragma unroll
        for (int mt = 0; mt < 4; ++mt)
            #pragma unroll
            for (int rg = 0; rg < 4; ++rg)
                s += fmaxf(acc[mt][nt][rg] + b3c[nt], 0.f);
        s += __shfl_xor(s, 16);
        s += __shfl_xor(s, 32);
        if (quad == 0)
            part[((size_t)(b * NTILE + tIdx)) * 256 + n0 + nt * 16 + lm] = s;
    }

    // ---- last block of this batch folds the f_phi tail ----
    __syncthreads();   // drains vmem (stores) before the counter bump
    if (tid == 0) {
        __threadfence();                       // release part stores
        int old = atomicAdd(&cnt[b], 1);
        lastFlag = (old == NTILE - 1);
    }
    __syncthreads();
    if (!lastFlag) return;
    __threadfence();                           // acquire: invalidate stale lines

    float* fs = (float*)tile;
    const float* pp = part + (size_t)b * NTILE * 256 + tid;
    float s = 0.f;
    #pragma unroll 8
    for (int t = 0; t < NTILE; ++t) s += pp[t * 256];
    fs[tid] = s;
    __syncthreads();
    float a1 = fb1[tid];
    #pragma unroll 8
    for (int k = 0; k < 256; ++k) a1 += fs[k] * fw1[k * 256 + tid];
    fs[256 + tid] = fmaxf(a1, 0.f);
    __syncthreads();
    float a2 = fb2[tid];
    #pragma unroll 8
    for (int k = 0; k < 256; ++k) a2 += fs[256 + k] * fw2[k * 256 + tid];
    fs[512 + tid] = fmaxf(a2, 0.f);
    __syncthreads();
    if (tid < 32) {
        float o = fb3[tid];
        #pragma unroll 8
        for (int k = 0; k < 256; ++k) o += fs[512 + k] * fw3[k * 32 + tid];
        out[b * 32 + tid] = o;
    }
}

extern "C" void kernel_launch(void* const* d_in, const int* in_sizes, int n_in,
                              void* d_out, int out_size, void* d_ws, size_t ws_size,
                              hipStream_t stream) {
    const float* x    = (const float*)d_in[0];
    const float* code = (const float*)d_in[1];
    const float* gw1  = (const float*)d_in[2];
    const float* gb1  = (const float*)d_in[3];
    const float* gw2  = (const float*)d_in[4];
    const float* gb2  = (const float*)d_in[5];
    const float* gw3  = (const float*)d_in[6];
    const float* gb3  = (const float*)d_in[7];
    const float* fw1  = (const float*)d_in[8];
    const float* fb1  = (const float*)d_in[9];
    const float* fw2  = (const float*)d_in[10];
    const float* fb2  = (const float*)d_in[11];
    const float* fw3  = (const float*)d_in[12];
    const float* fb3  = (const float*)d_in[13];
    float* out = (float*)d_out;

    // ws layout (bytes), total ~6.57 MB
    char* ws = (char*)d_ws;
    unsigned short* ub  = (unsigned short*)(ws);               // 1 MiB
    unsigned short* vb  = (unsigned short*)(ws + 1048576);     // 1 MiB
    unsigned short* w2t = (unsigned short*)(ws + 2097152);     // 128 KiB
    unsigned short* w3t = (unsigned short*)(ws + 2228224);     // 128 KiB
    float*          part= (float*)(ws + 2359296);              // 4,210,688 B
    int*            cnt = (int*)(ws + 6569984);                // 32 B

    hipLaunchKernelGGL(k_pre, dim3(2080), dim3(256), 0, stream,
                       x, code, gw1, gb1, gw2, gw3, ub, vb, w2t, w3t, cnt);
    hipLaunchKernelGGL(k_main, dim3(NTILE, 8), dim3(256), 0, stream,
                       ub, vb, w2t, w3t, gb2, gb3, part, cnt,
                       fw1, fb1, fw2, fb2, fw3, fb3, out);
}

// Round 4
// 313.070 us; speedup vs baseline: 1.2945x; 1.2945x over previous
//
#include <hip/hip_runtime.h>
#include <stdint.h>

// RelationalNetwork B=8 C=64 O=256 TE=128 GT=FP=256 A=32
// R4: 3 dispatches, NO fences/atomics. LDS bank fix via PADDED row stride
// (264 halfwords = 528 B => +4 banks/row): build & A-frag b128 = 8 lanes per
// 4-bank group (minimum), h2 b32 writeback = 2 lanes/bank (free). 64-row
// tiles, 33 KiB LDS -> 4 blocks/CU (16 waves). Coalesced part buffer.

#define NPAIR 32896
#define NTILE 514
#define STRH  264            // padded LDS row stride in halfwords

using short8  = __attribute__((ext_vector_type(8))) short;
using float4v = __attribute__((ext_vector_type(4))) float;

__device__ __forceinline__ float    asf(unsigned u){ union{unsigned u; float f;}c; c.u=u; return c.f; }
__device__ __forceinline__ unsigned asu(float f){ union{float f; unsigned u;}c; c.f=f; return c.u; }
__device__ __forceinline__ unsigned short f2bf(float f){
    unsigned u = asu(f); u += 0x7FFFu + ((u>>16)&1u); return (unsigned short)(u>>16);
}
// pack two floats -> bf16x2 (round-half-up), lo in low half
__device__ __forceinline__ unsigned pkhu(float lo, float hi){
    return __builtin_amdgcn_perm(asu(hi)+0x8000u, asu(lo)+0x8000u, 0x07060302u);
}
// relu(u+v) on packed bf16x2
__device__ __forceinline__ unsigned bfar2(unsigned u, unsigned v){
    float sh = fmaxf(asf(u & 0xffff0000u) + asf(v & 0xffff0000u), 0.f);
    float sl = fmaxf(asf(u << 16)         + asf(v << 16),         0.f);
    return pkhu(sl, sh);
}

// ---- prep: blocks 0..1023 U/V (2 batches each, w1 cols reused);
//      blocks 1024..1055 W2/W3 transpose+bf16 ------------------------------
__global__ __launch_bounds__(256) void k_pre(
    const float* __restrict__ x, const float* __restrict__ code,
    const float* __restrict__ w1, const float* __restrict__ b1,
    const float* __restrict__ w2, const float* __restrict__ w3,
    unsigned short* __restrict__ ub, unsigned short* __restrict__ vb,
    unsigned short* __restrict__ w2t, unsigned short* __restrict__ w3t)
{
    const int bx = blockIdx.x, tid = threadIdx.x;
    if (bx < 1024) {
        const int i = bx & 255, b0 = (bx >> 8) * 2;   // batches b0, b0+1
        const int d = tid;
        float su0 = b1[d], su1 = b1[d], sv0 = 0.f, sv1 = 0.f;
        const float* c0 = code + b0 * 128;
        const float* c1 = c0 + 128;
        #pragma unroll 8
        for (int t = 0; t < 128; ++t) {
            float w = w1[(132 + t) * 256 + d];
            su0 += c0[t] * w; su1 += c1[t] * w;
        }
        const float* x0 = x + b0 * 64 * 256 + i;
        const float* x1 = x0 + 64 * 256;
        #pragma unroll 4
        for (int c = 0; c < 64; ++c) {
            float wa = w1[c * 256 + d], wb = w1[(66 + c) * 256 + d];
            float xa = x0[c * 256],     xc = x1[c * 256];
            su0 += xa * wa; su1 += xc * wa;
            sv0 += xa * wb; sv1 += xc * wb;
        }
        float yy = (float)(i >> 4) * (2.f / 15.f) - 1.f;
        float xx = (float)(i & 15) * (2.f / 15.f) - 1.f;
        float cu = yy * w1[64 * 256 + d]  + xx * w1[65 * 256 + d];
        float cv = yy * w1[130 * 256 + d] + xx * w1[131 * 256 + d];
        ub[(b0 * 256 + i) * 256 + d]       = f2bf(su0 + cu);
        ub[((b0 + 1) * 256 + i) * 256 + d] = f2bf(su1 + cu);
        vb[(b0 * 256 + i) * 256 + d]       = f2bf(sv0 + cv);
        vb[((b0 + 1) * 256 + i) * 256 + d] = f2bf(sv1 + cv);
    } else {
        __shared__ float t[64][65];
        const int id = bx - 1024;
        const float* src = (id >= 16) ? w3 : w2;
        unsigned short* dst = (id >= 16) ? w3t : w2t;
        const int rem = id & 15;
        const int k0 = (rem >> 2) * 64, n0 = (rem & 3) * 64;
        const int tx = tid & 63, ty = tid >> 6;
        #pragma unroll
        for (int r = ty; r < 64; r += 4)
            t[r][tx] = src[(k0 + r) * 256 + n0 + tx];
        __syncthreads();
        #pragma unroll
        for (int r = ty; r < 64; r += 4)
            dst[(n0 + r) * 256 + k0 + tx] = f2bf(t[tx][r]);
    }
}

// ---- fused g_theta L2+L3 + tril row-sum ---------------------------------
__global__ __launch_bounds__(256, 4) void k_main(
    const unsigned short* __restrict__ ub, const unsigned short* __restrict__ vb,
    const unsigned short* __restrict__ w2t, const unsigned short* __restrict__ w3t,
    const float* __restrict__ b2, const float* __restrict__ b3,
    float* __restrict__ part)
{
    __shared__ unsigned short tile[64 * STRH];   // 33 KiB, padded stride
    const int tid  = threadIdx.x;
    const int b    = blockIdx.y, tIdx = blockIdx.x;
    const int lane = tid & 63, wave = tid >> 6;
    const int n0   = wave * 64;
    const int lm   = lane & 15, quad = lane >> 4;

    // ---- build h1 = relu(U_i + V_j) into LDS ----
    {
        const int r = tid >> 2, q4 = tid & 3;
        const int p = tIdx * 64 + r;
        float sq = sqrtf(8.f * (float)p + 1.f);
        int i = (int)((sq - 1.f) * 0.5f);
        while ((i + 1) * (i + 2) / 2 <= p) ++i;
        while (i * (i + 1) / 2 > p) --i;
        const int j = p - i * (i + 1) / 2;
        const unsigned short* up = ub + (b * 256 + i) * 256;
        const unsigned short* vp = vb + (b * 256 + j) * 256;
        #pragma unroll
        for (int it = 0; it < 8; ++it) {
            const int c = it * 4 + q4;
            uint4 u = *(const uint4*)(up + c * 8);
            uint4 v = *(const uint4*)(vp + c * 8);
            uint4 w;
            w.x = bfar2(u.x, v.x); w.y = bfar2(u.y, v.y);
            w.z = bfar2(u.z, v.z); w.w = bfar2(u.w, v.w);
            *(uint4*)(&tile[r * STRH + c * 8]) = w;
        }
    }
    __syncthreads();

    float b2c[4], b3c[4];
    #pragma unroll
    for (int nt = 0; nt < 4; ++nt) {
        b2c[nt] = b2[n0 + nt * 16 + lm];
        b3c[nt] = b3[n0 + nt * 16 + lm];
    }

    const float4v zero4 = {0.f, 0.f, 0.f, 0.f};
    float4v acc[4][4];
    #pragma unroll
    for (int mt = 0; mt < 4; ++mt)
        #pragma unroll
        for (int nt = 0; nt < 4; ++nt) acc[mt][nt] = zero4;

    // ---- GEMM1: h2 = h1 @ W2 ----
    const unsigned short* bb2 = w2t + (n0 + lm) * 256 + quad * 8;
    for (int ks = 0; ks < 8; ++ks) {
        short8 bfr[4];
        #pragma unroll
        for (int nt = 0; nt < 4; ++nt)
            bfr[nt] = *(const short8*)(bb2 + nt * 4096 + ks * 32);
        const int coff = (ks * 4 + quad) * 8;
        short8 afr[4];
        #pragma unroll
        for (int mt = 0; mt < 4; ++mt)
            afr[mt] = *(const short8*)(&tile[(mt * 16 + lm) * STRH + coff]);
        #pragma unroll
        for (int mt = 0; mt < 4; ++mt)
            #pragma unroll
            for (int nt = 0; nt < 4; ++nt)
                acc[mt][nt] = __builtin_amdgcn_mfma_f32_16x16x32_bf16(
                    afr[mt], bfr[nt], acc[mt][nt], 0, 0, 0);
    }
    __syncthreads();

    // ---- h2 = relu(acc + b2) -> LDS (paired b32 stores, 2 lanes/bank) ----
    #pragma unroll
    for (int mt = 0; mt < 4; ++mt) {
        #pragma unroll
        for (int nt = 0; nt < 4; ++nt) {
            const int colE = n0 + nt * 16 + (lm & ~1);
            #pragma unroll
            for (int rg = 0; rg < 4; ++rg) {
                const int row = mt * 16 + quad * 4 + rg;
                float v  = fmaxf(acc[mt][nt][rg] + b2c[nt], 0.f);
                float v1 = __shfl_down(v, 1);
                if (!(lm & 1))
                    *(unsigned*)(&tile[row * STRH + colE]) = pkhu(v, v1);
            }
        }
    }
    __syncthreads();

    // ---- GEMM2: rel = h2 @ W3 ----
    #pragma unroll
    for (int mt = 0; mt < 4; ++mt)
        #pragma unroll
        for (int nt = 0; nt < 4; ++nt) acc[mt][nt] = zero4;

    const unsigned short* bb3 = w3t + (n0 + lm) * 256 + quad * 8;
    for (int ks = 0; ks < 8; ++ks) {
        short8 bfr[4];
        #pragma unroll
        for (int nt = 0; nt < 4; ++nt)
            bfr[nt] = *(const short8*)(bb3 + nt * 4096 + ks * 32);
        const int coff = (ks * 4 + quad) * 8;
        short8 afr[4];
        #pragma unroll
        for (int mt = 0; mt < 4; ++mt)
            afr[mt] = *(const short8*)(&tile[(mt * 16 + lm) * STRH + coff]);
        #pragma unroll
        for (int mt = 0; mt < 4; ++mt)
            #pragma unroll
            for (int nt = 0; nt < 4; ++nt)
                acc[mt][nt] = __builtin_amdgcn_mfma_f32_16x16x32_bf16(
                    afr[mt], bfr[nt], acc[mt][nt], 0, 0, 0);
    }

    // ---- relu + row-sum -> coalesced partials (no atomics) ----
    #pragma unroll
    for (int nt = 0; nt < 4; ++nt) {
        float s = 0.f;
        #pragma unroll
        for (int mt = 0; mt < 4; ++mt)
            #pragma unroll
            for (int rg = 0; rg < 4; ++rg)
                s += fmaxf(acc[mt][nt][rg] + b3c[nt], 0.f);
        s += __shfl_xor(s, 16);
        s += __shfl_xor(s, 32);
        if (quad == 0)
            part[((size_t)(b * NTILE + tIdx)) * 256 + n0 + nt * 16 + lm] = s;
    }
}

// ---- reduce partials + f_phi (fp32) -------------------------------------
__global__ void k_tail(const float* __restrict__ part,
                       const float* __restrict__ fw1, const float* __restrict__ fb1,
                       const float* __restrict__ fw2, const float* __restrict__ fb2,
                       const float* __restrict__ fw3, const float* __restrict__ fb3,
                       float* __restrict__ out) {
    __shared__ float s0[256], s1[256];
    const int b = blockIdx.x, d = threadIdx.x;
    float s = 0.f;
    const float* pp = part + (size_t)b * NTILE * 256 + d;
    #pragma unroll 8
    for (int t = 0; t < NTILE; ++t) s += pp[t * 256];
    s0[d] = s;
    __syncthreads();
    float a1 = fb1[d];
    #pragma unroll 8
    for (int k = 0; k < 256; ++k) a1 += s0[k] * fw1[k * 256 + d];
    s1[d] = fmaxf(a1, 0.f);
    __syncthreads();
    float a2 = fb2[d];
    #pragma unroll 8
    for (int k = 0; k < 256; ++k) a2 += s1[k] * fw2[k * 256 + d];
    s0[d] = fmaxf(a2, 0.f);
    __syncthreads();
    if (d < 32) {
        float o = fb3[d];
        #pragma unroll 8
        for (int k = 0; k < 256; ++k) o += s0[k] * fw3[k * 32 + d];
        out[b * 32 + d] = o;
    }
}

extern "C" void kernel_launch(void* const* d_in, const int* in_sizes, int n_in,
                              void* d_out, int out_size, void* d_ws, size_t ws_size,
                              hipStream_t stream) {
    const float* x    = (const float*)d_in[0];
    const float* code = (const float*)d_in[1];
    const float* gw1  = (const float*)d_in[2];
    const float* gb1  = (const float*)d_in[3];
    const float* gw2  = (const float*)d_in[4];
    const float* gb2  = (const float*)d_in[5];
    const float* gw3  = (const float*)d_in[6];
    const float* gb3  = (const float*)d_in[7];
    const float* fw1  = (const float*)d_in[8];
    const float* fb1  = (const float*)d_in[9];
    const float* fw2  = (const float*)d_in[10];
    const float* fb2  = (const float*)d_in[11];
    const float* fw3  = (const float*)d_in[12];
    const float* fb3  = (const float*)d_in[13];
    float* out = (float*)d_out;

    // ws layout (bytes), total ~6.57 MB
    char* ws = (char*)d_ws;
    unsigned short* ub  = (unsigned short*)(ws);               // 1 MiB
    unsigned short* vb  = (unsigned short*)(ws + 1048576);     // 1 MiB
    unsigned short* w2t = (unsigned short*)(ws + 2097152);     // 128 KiB
    unsigned short* w3t = (unsigned short*)(ws + 2228224);     // 128 KiB
    float*          part= (float*)(ws + 2359296);              // 4,210,688 B

    hipLaunchKernelGGL(k_pre, dim3(1056), dim3(256), 0, stream,
                       x, code, gw1, gb1, gw2, gw3, ub, vb, w2t, w3t);
    hipLaunchKernelGGL(k_main, dim3(NTILE, 8), dim3(256), 0, stream,
                       ub, vb, w2t, w3t, gb2, gb3, part);
    hipLaunchKernelGGL(k_tail, dim3(8), dim3(256), 0, stream,
                       part, fw1, fb1, fw2, fb2, fw3, fb3, out);
}

// Round 5
// 283.754 us; speedup vs baseline: 1.4283x; 1.1033x over previous
//
#include <hip/hip_runtime.h>
#include <stdint.h>

// RelationalNetwork B=8 C=64 O=256 TE=128 GT=FP=256 A=32
// R5: k_main software-pipelined. launch_bounds(256,3) frees VGPRs (R4's
// (256,4) forced 64 VGPR -> zero pipelining -> 95% stall). 2-stage manual
// double-buffer on B(global)/A(LDS) frags; GEMM1 B ks=0 prefetched before
// build; GEMM2 B ks=0 prefetched before writeback. Padded LDS stride 264
// (real conflicts fixed in R4; residual SQ_LDS_BANK_CONFLICT ~5.3M is the
// structural b128 multi-cycle cost - not actionable). k_tail 1024-threads.

#define NPAIR 32896
#define NTILE 514
#define STRH  264            // padded LDS row stride in halfwords

using short8  = __attribute__((ext_vector_type(8))) short;
using float4v = __attribute__((ext_vector_type(4))) float;

__device__ __forceinline__ float    asf(unsigned u){ union{unsigned u; float f;}c; c.u=u; return c.f; }
__device__ __forceinline__ unsigned asu(float f){ union{float f; unsigned u;}c; c.f=f; return c.u; }
__device__ __forceinline__ unsigned short f2bf(float f){
    unsigned u = asu(f); u += 0x7FFFu + ((u>>16)&1u); return (unsigned short)(u>>16);
}
__device__ __forceinline__ unsigned pkhu(float lo, float hi){
    return __builtin_amdgcn_perm(asu(hi)+0x8000u, asu(lo)+0x8000u, 0x07060302u);
}
__device__ __forceinline__ unsigned bfar2(unsigned u, unsigned v){
    float sh = fmaxf(asf(u & 0xffff0000u) + asf(v & 0xffff0000u), 0.f);
    float sl = fmaxf(asf(u << 16)         + asf(v << 16),         0.f);
    return pkhu(sl, sh);
}

// ---- prep: blocks 0..1023 U/V (2 batches each); 1024..1055 W^T -----------
__global__ __launch_bounds__(256) void k_pre(
    const float* __restrict__ x, const float* __restrict__ code,
    const float* __restrict__ w1, const float* __restrict__ b1,
    const float* __restrict__ w2, const float* __restrict__ w3,
    unsigned short* __restrict__ ub, unsigned short* __restrict__ vb,
    unsigned short* __restrict__ w2t, unsigned short* __restrict__ w3t)
{
    const int bx = blockIdx.x, tid = threadIdx.x;
    if (bx < 1024) {
        const int i = bx & 255, b0 = (bx >> 8) * 2;
        const int d = tid;
        float su0 = b1[d], su1 = b1[d], sv0 = 0.f, sv1 = 0.f;
        const float* c0 = code + b0 * 128;
        const float* c1 = c0 + 128;
        #pragma unroll 8
        for (int t = 0; t < 128; ++t) {
            float w = w1[(132 + t) * 256 + d];
            su0 += c0[t] * w; su1 += c1[t] * w;
        }
        const float* x0 = x + b0 * 64 * 256 + i;
        const float* x1 = x0 + 64 * 256;
        #pragma unroll 4
        for (int c = 0; c < 64; ++c) {
            float wa = w1[c * 256 + d], wb = w1[(66 + c) * 256 + d];
            float xa = x0[c * 256],     xc = x1[c * 256];
            su0 += xa * wa; su1 += xc * wa;
            sv0 += xa * wb; sv1 += xc * wb;
        }
        float yy = (float)(i >> 4) * (2.f / 15.f) - 1.f;
        float xx = (float)(i & 15) * (2.f / 15.f) - 1.f;
        float cu = yy * w1[64 * 256 + d]  + xx * w1[65 * 256 + d];
        float cv = yy * w1[130 * 256 + d] + xx * w1[131 * 256 + d];
        ub[(b0 * 256 + i) * 256 + d]       = f2bf(su0 + cu);
        ub[((b0 + 1) * 256 + i) * 256 + d] = f2bf(su1 + cu);
        vb[(b0 * 256 + i) * 256 + d]       = f2bf(sv0 + cv);
        vb[((b0 + 1) * 256 + i) * 256 + d] = f2bf(sv1 + cv);
    } else {
        __shared__ float t[64][65];
        const int id = bx - 1024;
        const float* src = (id >= 16) ? w3 : w2;
        unsigned short* dst = (id >= 16) ? w3t : w2t;
        const int rem = id & 15;
        const int k0 = (rem >> 2) * 64, n0 = (rem & 3) * 64;
        const int tx = tid & 63, ty = tid >> 6;
        #pragma unroll
        for (int r = ty; r < 64; r += 4)
            t[r][tx] = src[(k0 + r) * 256 + n0 + tx];
        __syncthreads();
        #pragma unroll
        for (int r = ty; r < 64; r += 4)
            dst[(n0 + r) * 256 + k0 + tx] = f2bf(t[tx][r]);
    }
}

#define LOADB(dst, base, ksv) { \
    _Pragma("unroll") \
    for (int nt = 0; nt < 4; ++nt) \
        dst[nt] = *(const short8*)((base) + nt * 4096 + (ksv) * 32); }
#define LOADA(dst, ksv) { \
    _Pragma("unroll") \
    for (int mt = 0; mt < 4; ++mt) \
        dst[mt] = *(const short8*)(&tile[(mt * 16 + lm) * STRH + ((ksv) * 4 + quad) * 8]); }
#define MFMA16(bv, av) { \
    _Pragma("unroll") \
    for (int mt = 0; mt < 4; ++mt) \
        _Pragma("unroll") \
        for (int nt = 0; nt < 4; ++nt) \
            acc[mt][nt] = __builtin_amdgcn_mfma_f32_16x16x32_bf16( \
                av[mt], bv[nt], acc[mt][nt], 0, 0, 0); }

// ---- fused g_theta L2+L3 + tril row-sum, software-pipelined --------------
__global__ __launch_bounds__(256, 3) void k_main(
    const unsigned short* __restrict__ ub, const unsigned short* __restrict__ vb,
    const unsigned short* __restrict__ w2t, const unsigned short* __restrict__ w3t,
    const float* __restrict__ b2, const float* __restrict__ b3,
    float* __restrict__ part)
{
    __shared__ unsigned short tile[64 * STRH];   // 33 KiB
    const int tid  = threadIdx.x;
    const int b    = blockIdx.y, tIdx = blockIdx.x;
    const int lane = tid & 63, wave = tid >> 6;
    const int n0   = wave * 64;
    const int lm   = lane & 15, quad = lane >> 4;

    const unsigned short* bb2 = w2t + (n0 + lm) * 256 + quad * 8;
    const unsigned short* bb3 = w3t + (n0 + lm) * 256 + quad * 8;

    // prefetch GEMM1 B ks=0 before the build phase (no LDS dependency)
    short8 bA[4], bB[4], aA[4], aB[4];
    LOADB(bA, bb2, 0);

    // ---- build h1 = relu(U_i + V_j) into LDS: batch-issue all 16 loads ----
    {
        const int r = tid >> 2, q4 = tid & 3;
        const int p = tIdx * 64 + r;
        float sq = sqrtf(8.f * (float)p + 1.f);
        int i = (int)((sq - 1.f) * 0.5f);
        while ((i + 1) * (i + 2) / 2 <= p) ++i;
        while (i * (i + 1) / 2 > p) --i;
        const int j = p - i * (i + 1) / 2;
        const uint4* up = (const uint4*)(ub + (b * 256 + i) * 256) + q4;
        const uint4* vp = (const uint4*)(vb + (b * 256 + j) * 256) + q4;
        uint4 u[8], v[8];
        #pragma unroll
        for (int it = 0; it < 8; ++it) { u[it] = up[it * 4]; v[it] = vp[it * 4]; }
        #pragma unroll
        for (int it = 0; it < 8; ++it) {
            uint4 w;
            w.x = bfar2(u[it].x, v[it].x); w.y = bfar2(u[it].y, v[it].y);
            w.z = bfar2(u[it].z, v[it].z); w.w = bfar2(u[it].w, v[it].w);
            *(uint4*)(&tile[r * STRH + (it * 4 + q4) * 8]) = w;
        }
    }
    __syncthreads();

    float b2c[4], b3c[4];
    #pragma unroll
    for (int nt = 0; nt < 4; ++nt) {
        b2c[nt] = b2[n0 + nt * 16 + lm];
        b3c[nt] = b3[n0 + nt * 16 + lm];
    }

    const float4v zero4 = {0.f, 0.f, 0.f, 0.f};
    float4v acc[4][4];
    #pragma unroll
    for (int mt = 0; mt < 4; ++mt)
        #pragma unroll
        for (int nt = 0; nt < 4; ++nt) acc[mt][nt] = zero4;

    // ---- GEMM1: h2 = h1 @ W2, 2-stage pipeline ----
    LOADA(aA, 0);
    #pragma unroll
    for (int ks = 0; ks < 8; ks += 2) {
        LOADB(bB, bb2, ks + 1);
        LOADA(aB, ks + 1);
        MFMA16(bA, aA);
        if (ks + 2 < 8) {
            LOADB(bA, bb2, ks + 2);
            LOADA(aA, ks + 2);
        } else {
            LOADB(bA, bb3, 0);          // prefetch GEMM2 B ks=0
        }
        MFMA16(bB, aB);
    }
    __syncthreads();

    // ---- h2 = relu(acc + b2) -> LDS (paired b32 stores, 2 lanes/bank) ----
    #pragma unroll
    for (int mt = 0; mt < 4; ++mt) {
        #pragma unroll
        for (int nt = 0; nt < 4; ++nt) {
            const int colE = n0 + nt * 16 + (lm & ~1);
            #pragma unroll
            for (int rg = 0; rg < 4; ++rg) {
                const int row = mt * 16 + quad * 4 + rg;
                float v  = fmaxf(acc[mt][nt][rg] + b2c[nt], 0.f);
                float v1 = __shfl_down(v, 1);
                if (!(lm & 1))
                    *(unsigned*)(&tile[row * STRH + colE]) = pkhu(v, v1);
            }
        }
    }
    __syncthreads();

    // ---- GEMM2: rel = h2 @ W3, 2-stage pipeline (bA holds ks=0 B) ----
    #pragma unroll
    for (int mt = 0; mt < 4; ++mt)
        #pragma unroll
        for (int nt = 0; nt < 4; ++nt) acc[mt][nt] = zero4;

    LOADA(aA, 0);
    #pragma unroll
    for (int ks = 0; ks < 8; ks += 2) {
        LOADB(bB, bb3, ks + 1);
        LOADA(aB, ks + 1);
        MFMA16(bA, aA);
        if (ks + 2 < 8) {
            LOADB(bA, bb3, ks + 2);
            LOADA(aA, ks + 2);
        }
        MFMA16(bB, aB);
    }

    // ---- relu + row-sum -> coalesced partials ----
    #pragma unroll
    for (int nt = 0; nt < 4; ++nt) {
        float s = 0.f;
        #pragma unroll
        for (int mt = 0; mt < 4; ++mt)
            #pragma unroll
            for (int rg = 0; rg < 4; ++rg)
                s += fmaxf(acc[mt][nt][rg] + b3c[nt], 0.f);
        s += __shfl_xor(s, 16);
        s += __shfl_xor(s, 32);
        if (quad == 0)
            part[((size_t)(b * NTILE + tIdx)) * 256 + n0 + nt * 16 + lm] = s;
    }
}

// ---- reduce partials + f_phi, 1024 threads (4-way K-split) ---------------
__global__ __launch_bounds__(1024) void k_tail(
    const float* __restrict__ part,
    const float* __restrict__ fw1, const float* __restrict__ fb1,
    const float* __restrict__ fw2, const float* __restrict__ fb2,
    const float* __restrict__ fw3, const float* __restrict__ fb3,
    float* __restrict__ out)
{
    __shared__ float red[4 * 256];
    __shared__ float s0[256], s1[256];
    const int b = blockIdx.x;
    const int d = threadIdx.x & 255, seg = threadIdx.x >> 8;

    // tile reduction (514 tiles, 4-way split)
    float s = 0.f;
    const float* pp = part + (size_t)b * NTILE * 256 + d;
    for (int t = seg; t < NTILE; t += 4) s += pp[t * 256];
    red[seg * 256 + d] = s;
    __syncthreads();
    if (seg == 0) s0[d] = red[d] + red[256 + d] + red[512 + d] + red[768 + d];
    __syncthreads();

    // layer1
    float a = 0.f;
    #pragma unroll 8
    for (int k = seg * 64; k < seg * 64 + 64; ++k) a += s0[k] * fw1[k * 256 + d];
    red[seg * 256 + d] = a;
    __syncthreads();
    if (seg == 0)
        s1[d] = fmaxf(red[d] + red[256 + d] + red[512 + d] + red[768 + d] + fb1[d], 0.f);
    __syncthreads();

    // layer2 (result into s0 — all layer-1 reads of s0 completed pre-barrier)
    a = 0.f;
    #pragma unroll 8
    for (int k = seg * 64; k < seg * 64 + 64; ++k) a += s1[k] * fw2[k * 256 + d];
    red[seg * 256 + d] = a;
    __syncthreads();
    if (seg == 0)
        s0[d] = fmaxf(red[d] + red[256 + d] + red[512 + d] + red[768 + d] + fb2[d], 0.f);
    __syncthreads();

    // layer3 (256 -> 32)
    if (d < 32) {
        float o = 0.f;
        #pragma unroll 8
        for (int k = seg * 64; k < seg * 64 + 64; ++k) o += s0[k] * fw3[k * 32 + d];
        red[seg * 256 + d] = o;
    }
    __syncthreads();
    if (seg == 0 && d < 32)
        out[b * 32 + d] = red[d] + red[256 + d] + red[512 + d] + red[768 + d] + fb3[d];
}

extern "C" void kernel_launch(void* const* d_in, const int* in_sizes, int n_in,
                              void* d_out, int out_size, void* d_ws, size_t ws_size,
                              hipStream_t stream) {
    const float* x    = (const float*)d_in[0];
    const float* code = (const float*)d_in[1];
    const float* gw1  = (const float*)d_in[2];
    const float* gb1  = (const float*)d_in[3];
    const float* gw2  = (const float*)d_in[4];
    const float* gb2  = (const float*)d_in[5];
    const float* gw3  = (const float*)d_in[6];
    const float* gb3  = (const float*)d_in[7];
    const float* fw1  = (const float*)d_in[8];
    const float* fb1  = (const float*)d_in[9];
    const float* fw2  = (const float*)d_in[10];
    const float* fb2  = (const float*)d_in[11];
    const float* fw3  = (const float*)d_in[12];
    const float* fb3  = (const float*)d_in[13];
    float* out = (float*)d_out;

    char* ws = (char*)d_ws;
    unsigned short* ub  = (unsigned short*)(ws);               // 1 MiB
    unsigned short* vb  = (unsigned short*)(ws + 1048576);     // 1 MiB
    unsigned short* w2t = (unsigned short*)(ws + 2097152);     // 128 KiB
    unsigned short* w3t = (unsigned short*)(ws + 2228224);     // 128 KiB
    float*          part= (float*)(ws + 2359296);              // 4,210,688 B

    hipLaunchKernelGGL(k_pre, dim3(1056), dim3(256), 0, stream,
                       x, code, gw1, gb1, gw2, gw3, ub, vb, w2t, w3t);
    hipLaunchKernelGGL(k_main, dim3(NTILE, 8), dim3(256), 0, stream,
                       ub, vb, w2t, w3t, gb2, gb3, part);
    hipLaunchKernelGGL(k_tail, dim3(8), dim3(1024), 0, stream,
                       part, fw1, fb1, fw2, fb2, fw3, fb3, out);
}